// Round 11
// baseline (330.403 us; speedup 1.0000x reference)
//
#include <hip/hip_runtime.h>

// Problem constants: N=50000, E=600000, F=128, H=128, O=64, R=8
#define F_DIM 128
#define H_DIM 128
#define O_DIM 64
#define R_NUM 8

typedef __attribute__((ext_vector_type(8))) short bf16x8;
typedef __attribute__((ext_vector_type(4))) float f32x4;
typedef __attribute__((ext_vector_type(8))) unsigned short u16x8;

union V8 { bf16x8 v; short4 h[2]; };

__device__ __forceinline__ unsigned short f2b(float f) {
    unsigned u = __float_as_uint(f);
    u += 0x7FFFu + ((u >> 16) & 1u);   // RNE
    return (unsigned short)(u >> 16);
}
__device__ __forceinline__ float b2f(unsigned short b) {
    return __uint_as_float(((unsigned)b) << 16);
}

// ---- fused setup A: (dst,rel) degree count + per-block ew min/max ;
//      x -> bf16 ; both weight stacks transpose+convert. Grid MUST be 512. ----
__global__ __launch_bounds__(256) void setupA(
    const float* __restrict__ ew, const int* __restrict__ dst,
    const int* __restrict__ et, int E, int* __restrict__ deg2,
    float* __restrict__ bmn, float* __restrict__ bmx,
    const float* __restrict__ x, unsigned short* __restrict__ xb, long x4,
    const float* __restrict__ W1, const float* __restrict__ root1,
    const float* __restrict__ W2, const float* __restrict__ root2,
    unsigned short* __restrict__ wt1, unsigned short* __restrict__ wt2) {
    __shared__ float smn[256], smx[256];
    const int tid = threadIdx.x;
    const int gstride = gridDim.x * blockDim.x;
    int g0 = blockIdx.x * blockDim.x + tid;

    // phase 1: degree count + minmax partials
    float mn = 1e30f, mx = -1e30f;
    for (int i = g0; i < E; i += gstride) {
        atomicAdd(&deg2[dst[i] * R_NUM + et[i]], 1);
        float v = ew[i];
        mn = fminf(mn, v);
        mx = fmaxf(mx, v);
    }
    smn[tid] = mn; smx[tid] = mx;
    __syncthreads();
    for (int s = 128; s > 0; s >>= 1) {
        if (tid < s) {
            smn[tid] = fminf(smn[tid], smn[tid + s]);
            smx[tid] = fmaxf(smx[tid], smx[tid + s]);
        }
        __syncthreads();
    }
    if (tid == 0) { bmn[blockIdx.x] = smn[0]; bmx[blockIdx.x] = smx[0]; }

    // phase 2: x -> bf16 (float4 groups)
    for (long i = g0; i < x4; i += gstride) {
        float4 v = ((const float4*)x)[i];
        ushort4 o;
        o.x = f2b(v.x); o.y = f2b(v.y); o.z = f2b(v.z); o.w = f2b(v.w);
        ((ushort4*)xb)[i] = o;
    }

    // phase 3: weights -> transposed bf16
    const int n1 = 9 * 128 * 128, n2 = 9 * 64 * 128;
    for (int idx = g0; idx < n1 + n2; idx += gstride) {
        if (idx < n1) {
            int r = idx / (128 * 128), rem = idx % (128 * 128);
            int n = rem / 128, k = rem % 128;
            float v = (r < 8) ? W1[((size_t)r * 128 + k) * 128 + n]
                              : root1[(size_t)k * 128 + n];
            wt1[idx] = f2b(v);
        } else {
            int j = idx - n1;
            int r = j / (64 * 128), rem = j % (64 * 128);
            int n = rem / 128, k = rem % 128;
            float v = (r < 8) ? W2[((size_t)r * 128 + k) * 64 + n]
                              : root2[(size_t)k * 64 + n];
            wt2[j] = f2b(v);
        }
    }
}

// ---- scan1: per-2048-chunk exclusive scan of deg2 + fused invc ----
__global__ void scan1_kernel(const int* __restrict__ deg, int* __restrict__ rp,
                             int* __restrict__ bsum, float* __restrict__ invc,
                             int M, int N) {
    __shared__ int s[256];
    int base = blockIdx.x * 2048;
    int t = threadIdx.x;
    int v[8]; int loc = 0;
#pragma unroll
    for (int i = 0; i < 8; ++i) {
        int idx = base + t * 8 + i;
        v[i] = (idx < M) ? deg[idx] : 0;
        loc += v[i];
    }
    int node = blockIdx.x * 256 + t;
    if (node < N) invc[node] = 1.0f / (float)max(loc, 1);
    s[t] = loc;
    __syncthreads();
    for (int off = 1; off < 256; off <<= 1) {
        int x = (t >= off) ? s[t - off] : 0;
        __syncthreads();
        s[t] += x;
        __syncthreads();
    }
    int run = s[t] - loc;
#pragma unroll
    for (int i = 0; i < 8; ++i) {
        int idx = base + t * 8 + i;
        if (idx < M) rp[idx] = run;
        run += v[i];
    }
    if (t == 255) bsum[blockIdx.x] = s[255];
}

// ---- scan2 + global min/max reduce (single block) ----
// After this, rp2 stays CHUNK-LOCAL; consumers add bsum[i>>11] (scan3 folded).
__global__ void scan2_mm(int* bsum, int nb, const float* __restrict__ bmn,
                         const float* __restrict__ bmx, float* mm) {
    __shared__ int s[256];
    __shared__ float smn[256], smx[256];
    int t = threadIdx.x;
    int v = (t < nb) ? bsum[t] : 0;
    s[t] = v;
    smn[t] = fminf(bmn[t], bmn[t + 256]);
    smx[t] = fmaxf(bmx[t], bmx[t + 256]);
    __syncthreads();
    for (int off = 1; off < 256; off <<= 1) {
        int x = (t >= off) ? s[t - off] : 0;
        __syncthreads();
        s[t] += x;
        __syncthreads();
    }
    if (t < nb) bsum[t] = s[t] - v;
    for (int r = 128; r > 0; r >>= 1) {
        if (t < r) {
            smn[t] = fminf(smn[t], smn[t + r]);
            smx[t] = fmaxf(smx[t], smx[t + r]);
        }
        __syncthreads();
    }
    if (t == 0) { mm[0] = smn[0]; mm[1] = smx[0]; }
}

// ---- CSR fill: pos = (rp2[i]++ local) + bsum[i>>11] ;
//      erec = bf16(w_norm * invc[dst])<<17 | src   (4B record)
__global__ void fill2_kernel(const int* __restrict__ src, const int* __restrict__ dst,
                             const int* __restrict__ et, const float* __restrict__ ew,
                             const float* __restrict__ mm, const float* __restrict__ invc,
                             int* __restrict__ rp2, const int* __restrict__ bsum,
                             unsigned* __restrict__ erec, int E) {
    int e = blockIdx.x * blockDim.x + threadIdx.x;
    if (e >= E) return;
    int d = dst[e];
    int i = d * R_NUM + et[e];
    int pos = atomicAdd(&rp2[i], 1) + bsum[i >> 11];
    float mn = mm[0], mx = mm[1];
    unsigned wq = f2b((ew[e] - mn) / (mx - mn + 1e-8f) * invc[d]);
    erec[pos] = (wq << 17) | (unsigned)src[e];
}

// ---- gather: y[seg] = sum_{e in seg} w_premul * inp[src],  seg=(n,r) --------
// 16 lanes per segment, 8 channels (16B) each -> 1KB per wave load instr.
// Segment bounds reconstructed from chunk-local rp2 + bsum (scan3 folded).
__global__ __launch_bounds__(256) void gather_y(
    const int* __restrict__ rp2, const int* __restrict__ bsum,
    const unsigned* __restrict__ erec,
    const unsigned short* __restrict__ inp,
    unsigned short* __restrict__ y, int N) {
    int gid = blockIdx.x * 256 + threadIdx.x;
    int seg = gid >> 4;
    int n = seg >> 3;
    if (n >= N) return;
    int j = (gid & 15) * 8;
    int beg = (seg == 0) ? 0 : rp2[seg - 1] + bsum[(seg - 1) >> 11];
    int end = rp2[seg] + bsum[seg >> 11];
    float acc[8] = {0.f, 0.f, 0.f, 0.f, 0.f, 0.f, 0.f, 0.f};
    int k = beg;
    for (; k + 2 <= end; k += 2) {
        unsigned r0 = erec[k], r1 = erec[k + 1];
        float w0 = __uint_as_float((r0 >> 1) & 0x7FFF8000u);
        float w1 = __uint_as_float((r1 >> 1) & 0x7FFF8000u);
        u16x8 v0 = *(const u16x8*)(inp + (size_t)(r0 & 0x1FFFFu) * 128 + j);
        u16x8 v1 = *(const u16x8*)(inp + (size_t)(r1 & 0x1FFFFu) * 128 + j);
#pragma unroll
        for (int c = 0; c < 8; ++c) acc[c] += w0 * b2f(v0[c]);
#pragma unroll
        for (int c = 0; c < 8; ++c) acc[c] += w1 * b2f(v1[c]);
    }
    if (k < end) {
        unsigned r0 = erec[k];
        float w0 = __uint_as_float((r0 >> 1) & 0x7FFF8000u);
        u16x8 v0 = *(const u16x8*)(inp + (size_t)(r0 & 0x1FFFFu) * 128 + j);
#pragma unroll
        for (int c = 0; c < 8; ++c) acc[c] += w0 * b2f(v0[c]);
    }
    u16x8 o;
#pragma unroll
    for (int c = 0; c < 8; ++c) o[c] = f2b(acc[c]);
    *(u16x8*)(y + (size_t)seg * 128 + j) = o;
}

// =====================================================================
// gemm_y v3: out[n] = sum_{r<8} y[n][r] @ Wt[r] + inp[n] @ Wt[8] + bias
// Block = 64 nodes, 4 waves. Wave w owns col-tiles [w*NTW,(w+1)*NTW):
// A-frags from L2-hot global into regs. y-slice double-buffered in LDS.
// ISSUE ORDER FIX vs R10: A-frags issued FIRST, y-prefetch SECOND ->
// MFMA waits vmcnt(4) (A only); prefetch stays in flight during MFMA
// and drains at the post-MFMA LDS commit (m135 in-order vmcnt semantics).
// MFMA roles (verified R4-R10): A=Wt frag (l15->out-col), B=y frag
// (l15->node), D: col=node, row=quad*4+i=out-col.
// =====================================================================
template <int NCOL, bool RELU, bool OUTB>
__global__ __launch_bounds__(256) void gemm_y(
    const unsigned short* __restrict__ y,     // N x 8 x 128 bf16
    const unsigned short* __restrict__ inp,   // N x 128 bf16 (self/root rows)
    const unsigned short* __restrict__ Wt,    // 9 x NCOL x 128 bf16
    const float* __restrict__ bias,
    unsigned short* __restrict__ outb, float* __restrict__ outf, int N)
{
    constexpr int NTW = NCOL / 64;            // col-tiles per wave (2 or 1)
    __shared__ unsigned short ybuf[2][64 * 132];

    const int tid = threadIdx.x;
    const int w = tid >> 6, lane = tid & 63;
    const int quad = lane >> 4, l15 = lane & 15;
    const int n0 = blockIdx.x * 64;

    const int srow = tid >> 4;          // 0..15 (+ it*16)
    const int sseg = tid & 15;

    f32x4 acc[4][NTW];
#pragma unroll
    for (int m = 0; m < 4; ++m)
#pragma unroll
        for (int nt = 0; nt < NTW; ++nt) acc[m][nt] = (f32x4){0.f, 0.f, 0.f, 0.f};

    // ---- stage r=0 into buf 0 ----
#pragma unroll
    for (int it = 0; it < 4; ++it) {
        int row = srow + it * 16;
        int node = n0 + row;
        if (node >= N) node = N - 1;
        V8 v;
        v.v = *(const bf16x8*)(y + ((size_t)node * R_NUM + 0) * 128 + sseg * 8);
        *(short4*)&ybuf[0][row * 132 + sseg * 8]     = v.h[0];
        *(short4*)&ybuf[0][row * 132 + sseg * 8 + 4] = v.h[1];
    }
    __syncthreads();

    for (int r = 0; r < 9; ++r) {
        const int buf = r & 1;
        // ---- A-frags for this r from global: issued FIRST (oldest) ----
        bf16x8 afr[NTW][4];
#pragma unroll
        for (int nt = 0; nt < NTW; ++nt)
#pragma unroll
            for (int k2 = 0; k2 < 4; ++k2)
                afr[nt][k2] = *(const bf16x8*)(
                    Wt + ((size_t)r * NCOL + (w * NTW + nt) * 16 + l15) * 128
                       + k2 * 32 + quad * 8);
        // ---- y-prefetch for r+1: issued SECOND (stays in flight) ----
        V8 pre[4];
        if (r < 8) {
            const int rn = r + 1;
#pragma unroll
            for (int it = 0; it < 4; ++it) {
                int row = srow + it * 16;
                int node = n0 + row;
                if (node >= N) node = N - 1;
                const unsigned short* src = (rn < 8)
                    ? y + ((size_t)node * R_NUM + rn) * 128 + sseg * 8
                    : inp + (size_t)node * 128 + sseg * 8;
                pre[it].v = *(const bf16x8*)src;
            }
        }
        // ---- MFMA over 4 node tiles (waits only for afr) ----
#pragma unroll
        for (int m = 0; m < 4; ++m) {
            const unsigned short* yrow = &ybuf[buf][(m * 16 + l15) * 132 + quad * 8];
#pragma unroll
            for (int k2 = 0; k2 < 4; ++k2) {
                V8 b;
                b.h[0] = *(const short4*)(yrow + k2 * 32);
                b.h[1] = *(const short4*)(yrow + k2 * 32 + 4);
#pragma unroll
                for (int nt = 0; nt < NTW; ++nt)
                    acc[m][nt] = __builtin_amdgcn_mfma_f32_16x16x32_bf16(
                        afr[nt][k2], b.v, acc[m][nt], 0, 0, 0);
            }
        }
        // ---- commit prefetch (drains here, after MFMA), single barrier ----
        if (r < 8) {
#pragma unroll
            for (int it = 0; it < 4; ++it) {
                int row = srow + it * 16;
                *(short4*)&ybuf[buf ^ 1][row * 132 + sseg * 8]     = pre[it].h[0];
                *(short4*)&ybuf[buf ^ 1][row * 132 + sseg * 8 + 4] = pre[it].h[1];
            }
        }
        __syncthreads();
    }

    // ---- epilogue: bias (+relu), LDS transpose, coalesced store ----
    const int gn = tid >> 2, gq = tid & 3;
    const int gnode = n0 + gn;
    if (OUTB) {
        unsigned short* stg = &ybuf[0][0];   // 64 x 136
#pragma unroll
        for (int m = 0; m < 4; ++m)
#pragma unroll
            for (int nt = 0; nt < NTW; ++nt) {
                int node_l = m * 16 + l15;
                int c0 = (w * NTW + nt) * 16 + quad * 4;
                float4 bs = *(const float4*)(bias + c0);
                float v0 = acc[m][nt][0] + bs.x, v1 = acc[m][nt][1] + bs.y;
                float v2 = acc[m][nt][2] + bs.z, v3 = acc[m][nt][3] + bs.w;
                if (RELU) {
                    v0 = fmaxf(v0, 0.f); v1 = fmaxf(v1, 0.f);
                    v2 = fmaxf(v2, 0.f); v3 = fmaxf(v3, 0.f);
                }
                short4 o;
                o.x = (short)f2b(v0); o.y = (short)f2b(v1);
                o.z = (short)f2b(v2); o.w = (short)f2b(v3);
                *(short4*)&stg[node_l * 136 + c0] = o;
            }
        __syncthreads();
        if (gnode < N) {
            const unsigned short* srw = stg + gn * 136 + gq * (NCOL / 4);
            unsigned short* drow = outb + (size_t)gnode * NCOL + gq * (NCOL / 4);
#pragma unroll
            for (int c = 0; c < NCOL / 32; ++c)
                *(bf16x8*)(drow + c * 8) = *(const bf16x8*)(srw + c * 8);
        }
    } else {
        float* stg = (float*)&ybuf[0][0];    // 64 x 68 floats
#pragma unroll
        for (int m = 0; m < 4; ++m)
#pragma unroll
            for (int nt = 0; nt < NTW; ++nt) {
                int node_l = m * 16 + l15;
                int c0 = (w * NTW + nt) * 16 + quad * 4;
                float4 bs = *(const float4*)(bias + c0);
                float v0 = acc[m][nt][0] + bs.x, v1 = acc[m][nt][1] + bs.y;
                float v2 = acc[m][nt][2] + bs.z, v3 = acc[m][nt][3] + bs.w;
                if (RELU) {
                    v0 = fmaxf(v0, 0.f); v1 = fmaxf(v1, 0.f);
                    v2 = fmaxf(v2, 0.f); v3 = fmaxf(v3, 0.f);
                }
                *(float4*)&stg[node_l * 68 + c0] = make_float4(v0, v1, v2, v3);
            }
        __syncthreads();
        if (gnode < N) {
            const float* srw = stg + gn * 68 + gq * (NCOL / 4);
            float* drow = outf + (size_t)gnode * NCOL + gq * (NCOL / 4);
#pragma unroll
            for (int c = 0; c < NCOL / 16; ++c)
                *(float4*)(drow + c * 4) = *(const float4*)(srw + c * 4);
        }
    }
}

extern "C" void kernel_launch(void* const* d_in, const int* in_sizes, int n_in,
                              void* d_out, int out_size, void* d_ws, size_t ws_size,
                              hipStream_t stream) {
    const float* x     = (const float*)d_in[0];
    const int*   ei    = (const int*)d_in[1];
    const float* ew    = (const float*)d_in[2];
    const int*   et    = (const int*)d_in[3];
    const float* W1    = (const float*)d_in[4];
    const float* root1 = (const float*)d_in[5];
    const float* bias1 = (const float*)d_in[6];
    const float* W2    = (const float*)d_in[7];
    const float* root2 = (const float*)d_in[8];
    const float* bias2 = (const float*)d_in[9];

    const int N = in_sizes[0] / F_DIM;
    const int E = in_sizes[2];
    const int M2 = N * R_NUM;
    const int* srcp = ei;
    const int* dstp = ei + E;

    // ws layout (int units unless noted):
    // mm[16] | invc[N] | deg2[8N] | rp2[8N] | bsum[256] | bmn[512] | bmx[512] |
    // erec[E] | xb[N*128 u16] | hb[N*128 u16] | wt1[9*128*128 u16] |
    // wt2[9*64*128 u16] | y[N*1024 u16]
    int* base = (int*)d_ws;
    float* mm    = (float*)base;
    float* invc  = (float*)(base + 16);
    int*   deg2  = base + 16 + N;
    int*   rp2   = deg2 + M2;
    int*   bsum  = rp2 + M2;
    float* bmn   = (float*)(bsum + 256);
    float* bmx   = bmn + 512;
    unsigned* erec = (unsigned*)(bmx + 512);
    unsigned short* xb  = (unsigned short*)(erec + E);
    unsigned short* hb  = xb + (size_t)N * 128;
    unsigned short* wt1 = hb + (size_t)N * 128;
    unsigned short* wt2 = wt1 + 9 * 128 * 128;
    unsigned short* y   = wt2 + 9 * 64 * 128;   // N * 8 * 128

    const int TB = 256;
    int blocksE = (E + TB - 1) / TB;
    int nb = (M2 + 2047) / 2048;   // 196 <= 256
    long x4 = (long)N * 128 / 4;

    // ---- setup (5 launches; scan3 folded into fill2/gather) ----
    hipMemsetAsync(deg2, 0, (size_t)M2 * sizeof(int), stream);
    setupA<<<512, TB, 0, stream>>>(ew, dstp, et, E, deg2, bmn, bmx,
                                   x, xb, x4, W1, root1, W2, root2, wt1, wt2);
    scan1_kernel<<<nb, TB, 0, stream>>>(deg2, rp2, bsum, invc, M2, N);
    scan2_mm<<<1, TB, 0, stream>>>(bsum, nb, bmn, bmx, mm);
    fill2_kernel<<<blocksE, TB, 0, stream>>>(srcp, dstp, et, ew, mm, invc,
                                             rp2, bsum, erec, E);

    int gatB = (int)(((long)M2 * 16 + TB - 1) / TB);   // 25000
    int gB = (N + 63) / 64;                            // 782

    // ---- layer 1: 128 -> 128, relu, bf16 out ----
    gather_y<<<gatB, TB, 0, stream>>>(rp2, bsum, erec, xb, y, N);
    gemm_y<H_DIM, true, true><<<gB, TB, 0, stream>>>(y, xb, wt1, bias1, hb, nullptr, N);
    // ---- layer 2: 128 -> 64, f32 out ----
    gather_y<<<gatB, TB, 0, stream>>>(rp2, bsum, erec, hb, y, N);
    gemm_y<O_DIM, false, false><<<gB, TB, 0, stream>>>(y, hb, wt2, bias2, nullptr,
                                                       (float*)d_out, N);
}

// Round 12
// 323.278 us; speedup vs baseline: 1.0220x; 1.0220x over previous
//
#include <hip/hip_runtime.h>

// Problem constants: N=50000, E=600000, F=128, H=128, O=64, R=8
#define F_DIM 128
#define H_DIM 128
#define O_DIM 64
#define R_NUM 8

typedef __attribute__((ext_vector_type(8))) short bf16x8;
typedef __attribute__((ext_vector_type(4))) float f32x4;
typedef __attribute__((ext_vector_type(8))) unsigned short u16x8;

union V8 { bf16x8 v; short4 h[2]; };

__device__ __forceinline__ unsigned short f2b(float f) {
    unsigned u = __float_as_uint(f);
    u += 0x7FFFu + ((u >> 16) & 1u);   // RNE
    return (unsigned short)(u >> 16);
}
__device__ __forceinline__ float b2f(unsigned short b) {
    return __uint_as_float(((unsigned)b) << 16);
}

// ---- fused setup A: (dst,rel) degree count + per-block ew min/max ;
//      x -> bf16 ; both weight stacks transpose+convert. Grid MUST be 512. ----
__global__ __launch_bounds__(256) void setupA(
    const float* __restrict__ ew, const int* __restrict__ dst,
    const int* __restrict__ et, int E, int* __restrict__ deg2,
    float* __restrict__ bmn, float* __restrict__ bmx,
    const float* __restrict__ x, unsigned short* __restrict__ xb, long x4,
    const float* __restrict__ W1, const float* __restrict__ root1,
    const float* __restrict__ W2, const float* __restrict__ root2,
    unsigned short* __restrict__ wt1, unsigned short* __restrict__ wt2) {
    __shared__ float smn[256], smx[256];
    const int tid = threadIdx.x;
    const int gstride = gridDim.x * blockDim.x;
    int g0 = blockIdx.x * blockDim.x + tid;

    // phase 1: degree count + minmax partials
    float mn = 1e30f, mx = -1e30f;
    for (int i = g0; i < E; i += gstride) {
        atomicAdd(&deg2[dst[i] * R_NUM + et[i]], 1);
        float v = ew[i];
        mn = fminf(mn, v);
        mx = fmaxf(mx, v);
    }
    smn[tid] = mn; smx[tid] = mx;
    __syncthreads();
    for (int s = 128; s > 0; s >>= 1) {
        if (tid < s) {
            smn[tid] = fminf(smn[tid], smn[tid + s]);
            smx[tid] = fmaxf(smx[tid], smx[tid + s]);
        }
        __syncthreads();
    }
    if (tid == 0) { bmn[blockIdx.x] = smn[0]; bmx[blockIdx.x] = smx[0]; }

    // phase 2: x -> bf16 (float4 groups)
    for (long i = g0; i < x4; i += gstride) {
        float4 v = ((const float4*)x)[i];
        ushort4 o;
        o.x = f2b(v.x); o.y = f2b(v.y); o.z = f2b(v.z); o.w = f2b(v.w);
        ((ushort4*)xb)[i] = o;
    }

    // phase 3: weights -> transposed bf16
    const int n1 = 9 * 128 * 128, n2 = 9 * 64 * 128;
    for (int idx = g0; idx < n1 + n2; idx += gstride) {
        if (idx < n1) {
            int r = idx / (128 * 128), rem = idx % (128 * 128);
            int n = rem / 128, k = rem % 128;
            float v = (r < 8) ? W1[((size_t)r * 128 + k) * 128 + n]
                              : root1[(size_t)k * 128 + n];
            wt1[idx] = f2b(v);
        } else {
            int j = idx - n1;
            int r = j / (64 * 128), rem = j % (64 * 128);
            int n = rem / 128, k = rem % 128;
            float v = (r < 8) ? W2[((size_t)r * 128 + k) * 64 + n]
                              : root2[(size_t)k * 64 + n];
            wt2[j] = f2b(v);
        }
    }
}

// ---- scan1: per-2048-chunk exclusive scan of deg2 + fused invc ----
__global__ void scan1_kernel(const int* __restrict__ deg, int* __restrict__ rp,
                             int* __restrict__ bsum, float* __restrict__ invc,
                             int M, int N) {
    __shared__ int s[256];
    int base = blockIdx.x * 2048;
    int t = threadIdx.x;
    int v[8]; int loc = 0;
#pragma unroll
    for (int i = 0; i < 8; ++i) {
        int idx = base + t * 8 + i;
        v[i] = (idx < M) ? deg[idx] : 0;
        loc += v[i];
    }
    int node = blockIdx.x * 256 + t;
    if (node < N) invc[node] = 1.0f / (float)max(loc, 1);
    s[t] = loc;
    __syncthreads();
    for (int off = 1; off < 256; off <<= 1) {
        int x = (t >= off) ? s[t - off] : 0;
        __syncthreads();
        s[t] += x;
        __syncthreads();
    }
    int run = s[t] - loc;
#pragma unroll
    for (int i = 0; i < 8; ++i) {
        int idx = base + t * 8 + i;
        if (idx < M) rp[idx] = run;
        run += v[i];
    }
    if (t == 255) bsum[blockIdx.x] = s[255];
}

// ---- scan2 + global min/max reduce (single block) ----
// After this, rp2 stays CHUNK-LOCAL; consumers add bsum[i>>11] (scan3 folded).
__global__ void scan2_mm(int* bsum, int nb, const float* __restrict__ bmn,
                         const float* __restrict__ bmx, float* mm) {
    __shared__ int s[256];
    __shared__ float smn[256], smx[256];
    int t = threadIdx.x;
    int v = (t < nb) ? bsum[t] : 0;
    s[t] = v;
    smn[t] = fminf(bmn[t], bmn[t + 256]);
    smx[t] = fmaxf(bmx[t], bmx[t + 256]);
    __syncthreads();
    for (int off = 1; off < 256; off <<= 1) {
        int x = (t >= off) ? s[t - off] : 0;
        __syncthreads();
        s[t] += x;
        __syncthreads();
    }
    if (t < nb) bsum[t] = s[t] - v;
    for (int r = 128; r > 0; r >>= 1) {
        if (t < r) {
            smn[t] = fminf(smn[t], smn[t + r]);
            smx[t] = fmaxf(smx[t], smx[t + r]);
        }
        __syncthreads();
    }
    if (t == 0) { mm[0] = smn[0]; mm[1] = smx[0]; }
}

// ---- CSR fill: pos = (rp2[i]++ local) + bsum[i>>11] ;
//      erec = bf16(w_norm * invc[dst])<<17 | src   (4B record)
__global__ void fill2_kernel(const int* __restrict__ src, const int* __restrict__ dst,
                             const int* __restrict__ et, const float* __restrict__ ew,
                             const float* __restrict__ mm, const float* __restrict__ invc,
                             int* __restrict__ rp2, const int* __restrict__ bsum,
                             unsigned* __restrict__ erec, int E) {
    int e = blockIdx.x * blockDim.x + threadIdx.x;
    if (e >= E) return;
    int d = dst[e];
    int i = d * R_NUM + et[e];
    int pos = atomicAdd(&rp2[i], 1) + bsum[i >> 11];
    float mn = mm[0], mx = mm[1];
    unsigned wq = f2b((ew[e] - mn) / (mx - mn + 1e-8f) * invc[d]);
    erec[pos] = (wq << 17) | (unsigned)src[e];
}

// ---- gather: y[seg] = sum_{e in seg} w_premul * inp[src],  seg=(n,r) --------
__global__ __launch_bounds__(256) void gather_y(
    const int* __restrict__ rp2, const int* __restrict__ bsum,
    const unsigned* __restrict__ erec,
    const unsigned short* __restrict__ inp,
    unsigned short* __restrict__ y, int N) {
    int gid = blockIdx.x * 256 + threadIdx.x;
    int seg = gid >> 4;
    int n = seg >> 3;
    if (n >= N) return;
    int j = (gid & 15) * 8;
    int beg = (seg == 0) ? 0 : rp2[seg - 1] + bsum[(seg - 1) >> 11];
    int end = rp2[seg] + bsum[seg >> 11];
    float acc[8] = {0.f, 0.f, 0.f, 0.f, 0.f, 0.f, 0.f, 0.f};
    int k = beg;
    for (; k + 2 <= end; k += 2) {
        unsigned r0 = erec[k], r1 = erec[k + 1];
        float w0 = __uint_as_float((r0 >> 1) & 0x7FFF8000u);
        float w1 = __uint_as_float((r1 >> 1) & 0x7FFF8000u);
        u16x8 v0 = *(const u16x8*)(inp + (size_t)(r0 & 0x1FFFFu) * 128 + j);
        u16x8 v1 = *(const u16x8*)(inp + (size_t)(r1 & 0x1FFFFu) * 128 + j);
#pragma unroll
        for (int c = 0; c < 8; ++c) acc[c] += w0 * b2f(v0[c]);
#pragma unroll
        for (int c = 0; c < 8; ++c) acc[c] += w1 * b2f(v1[c]);
    }
    if (k < end) {
        unsigned r0 = erec[k];
        float w0 = __uint_as_float((r0 >> 1) & 0x7FFF8000u);
        u16x8 v0 = *(const u16x8*)(inp + (size_t)(r0 & 0x1FFFFu) * 128 + j);
#pragma unroll
        for (int c = 0; c < 8; ++c) acc[c] += w0 * b2f(v0[c]);
    }
    u16x8 o;
#pragma unroll
    for (int c = 0; c < 8; ++c) o[c] = f2b(acc[c]);
    *(u16x8*)(y + (size_t)seg * 128 + j) = o;
}

// =====================================================================
// gemm_y v4: out[n] = sum_{r<8} y[n][r] @ Wt[r] + inp[n] @ Wt[8] + bias
// Block = 64 nodes, 4 waves, wave w owns col-tiles [w*NTW,(w+1)*NTW).
// Software pipeline: A-frags register-DOUBLE-BUFFERED (afr[2][..]),
// y-slice LDS double-buffered. Iteration r issues loads for r+1 (Wt +
// y) then MFMAs entirely from afr[cur] regs + LDS cur buffer -> the
// compute phase has ZERO vmcnt dependence; loads drain at the commit.
// MFMA roles (verified R4-R11): A=Wt frag (l15->out-col), B=y frag
// (l15->node), D: col=node, row=quad*4+i=out-col.
// =====================================================================
template <int NCOL, bool RELU, bool OUTB>
__global__ __launch_bounds__(256) void gemm_y(
    const unsigned short* __restrict__ y,     // N x 8 x 128 bf16
    const unsigned short* __restrict__ inp,   // N x 128 bf16 (self/root rows)
    const unsigned short* __restrict__ Wt,    // 9 x NCOL x 128 bf16
    const float* __restrict__ bias,
    unsigned short* __restrict__ outb, float* __restrict__ outf, int N)
{
    constexpr int NTW = NCOL / 64;            // col-tiles per wave (2 or 1)
    __shared__ unsigned short ybuf[2][64 * 132];

    const int tid = threadIdx.x;
    const int w = tid >> 6, lane = tid & 63;
    const int quad = lane >> 4, l15 = lane & 15;
    const int n0 = blockIdx.x * 64;

    const int srow = tid >> 4;          // 0..15 (+ it*16)
    const int sseg = tid & 15;

    // clamped node for staging loads (stores guarded separately)
    int snode[4];
#pragma unroll
    for (int it = 0; it < 4; ++it) {
        int node = n0 + srow + it * 16;
        snode[it] = (node >= N) ? N - 1 : node;
    }

    f32x4 acc[4][NTW];
#pragma unroll
    for (int m = 0; m < 4; ++m)
#pragma unroll
        for (int nt = 0; nt < NTW; ++nt) acc[m][nt] = (f32x4){0.f, 0.f, 0.f, 0.f};

    // ---- preload: afr[0] (r=0 Wt frags) + stage y r=0 into buf 0 ----
    bf16x8 afr[2][NTW][4];
#pragma unroll
    for (int nt = 0; nt < NTW; ++nt)
#pragma unroll
        for (int k2 = 0; k2 < 4; ++k2)
            afr[0][nt][k2] = *(const bf16x8*)(
                Wt + ((size_t)(w * NTW + nt) * 16 + l15) * 128 + k2 * 32 + quad * 8);
#pragma unroll
    for (int it = 0; it < 4; ++it) {
        V8 v;
        v.v = *(const bf16x8*)(y + ((size_t)snode[it] * R_NUM + 0) * 128 + sseg * 8);
        int row = srow + it * 16;
        *(short4*)&ybuf[0][row * 132 + sseg * 8]     = v.h[0];
        *(short4*)&ybuf[0][row * 132 + sseg * 8 + 4] = v.h[1];
    }
    __syncthreads();

#pragma unroll
    for (int r = 0; r < 9; ++r) {
        const int cur = r & 1, nxt = cur ^ 1;
        // ---- issue loads for r+1: Wt frags into afr[nxt], y into pre ----
        V8 pre[4];
        if (r < 8) {
            const int rn = r + 1;
#pragma unroll
            for (int nt = 0; nt < NTW; ++nt)
#pragma unroll
                for (int k2 = 0; k2 < 4; ++k2)
                    afr[nxt][nt][k2] = *(const bf16x8*)(
                        Wt + ((size_t)rn * NCOL + (w * NTW + nt) * 16 + l15) * 128
                           + k2 * 32 + quad * 8);
#pragma unroll
            for (int it = 0; it < 4; ++it) {
                const unsigned short* src = (rn < 8)
                    ? y + ((size_t)snode[it] * R_NUM + rn) * 128 + sseg * 8
                    : inp + (size_t)snode[it] * 128 + sseg * 8;
                pre[it].v = *(const bf16x8*)src;
            }
        }
        // ---- MFMA: afr[cur] regs + LDS cur buffer -> no vmcnt waits ----
#pragma unroll
        for (int m = 0; m < 4; ++m) {
            const unsigned short* yrow = &ybuf[cur][(m * 16 + l15) * 132 + quad * 8];
#pragma unroll
            for (int k2 = 0; k2 < 4; ++k2) {
                V8 b;
                b.h[0] = *(const short4*)(yrow + k2 * 32);
                b.h[1] = *(const short4*)(yrow + k2 * 32 + 4);
#pragma unroll
                for (int nt = 0; nt < NTW; ++nt)
                    acc[m][nt] = __builtin_amdgcn_mfma_f32_16x16x32_bf16(
                        afr[cur][nt][k2], b.v, acc[m][nt], 0, 0, 0);
            }
        }
        // ---- commit y prefetch (loads drain here, after MFMA) ----
        if (r < 8) {
#pragma unroll
            for (int it = 0; it < 4; ++it) {
                int row = srow + it * 16;
                *(short4*)&ybuf[nxt][row * 132 + sseg * 8]     = pre[it].h[0];
                *(short4*)&ybuf[nxt][row * 132 + sseg * 8 + 4] = pre[it].h[1];
            }
        }
        __syncthreads();
    }

    // ---- epilogue: bias (+relu), LDS transpose, coalesced store ----
    const int gn = tid >> 2, gq = tid & 3;
    const int gnode = n0 + gn;
    if (OUTB) {
        unsigned short* stg = &ybuf[0][0];   // 64 x 136 (spans both buffers)
#pragma unroll
        for (int m = 0; m < 4; ++m)
#pragma unroll
            for (int nt = 0; nt < NTW; ++nt) {
                int node_l = m * 16 + l15;
                int c0 = (w * NTW + nt) * 16 + quad * 4;
                float4 bs = *(const float4*)(bias + c0);
                float v0 = acc[m][nt][0] + bs.x, v1 = acc[m][nt][1] + bs.y;
                float v2 = acc[m][nt][2] + bs.z, v3 = acc[m][nt][3] + bs.w;
                if (RELU) {
                    v0 = fmaxf(v0, 0.f); v1 = fmaxf(v1, 0.f);
                    v2 = fmaxf(v2, 0.f); v3 = fmaxf(v3, 0.f);
                }
                short4 o;
                o.x = (short)f2b(v0); o.y = (short)f2b(v1);
                o.z = (short)f2b(v2); o.w = (short)f2b(v3);
                *(short4*)&stg[node_l * 136 + c0] = o;
            }
        __syncthreads();
        if (gnode < N) {
            const unsigned short* srw = stg + gn * 136 + gq * (NCOL / 4);
            unsigned short* drow = outb + (size_t)gnode * NCOL + gq * (NCOL / 4);
#pragma unroll
            for (int c = 0; c < NCOL / 32; ++c)
                *(bf16x8*)(drow + c * 8) = *(const bf16x8*)(srw + c * 8);
        }
    } else {
        float* stg = (float*)&ybuf[0][0];    // 64 x 68 floats (spans both)
#pragma unroll
        for (int m = 0; m < 4; ++m)
#pragma unroll
            for (int nt = 0; nt < NTW; ++nt) {
                int node_l = m * 16 + l15;
                int c0 = (w * NTW + nt) * 16 + quad * 4;
                float4 bs = *(const float4*)(bias + c0);
                float v0 = acc[m][nt][0] + bs.x, v1 = acc[m][nt][1] + bs.y;
                float v2 = acc[m][nt][2] + bs.z, v3 = acc[m][nt][3] + bs.w;
                if (RELU) {
                    v0 = fmaxf(v0, 0.f); v1 = fmaxf(v1, 0.f);
                    v2 = fmaxf(v2, 0.f); v3 = fmaxf(v3, 0.f);
                }
                *(float4*)&stg[node_l * 68 + c0] = make_float4(v0, v1, v2, v3);
            }
        __syncthreads();
        if (gnode < N) {
            const float* srw = stg + gn * 68 + gq * (NCOL / 4);
            float* drow = outf + (size_t)gnode * NCOL + gq * (NCOL / 4);
#pragma unroll
            for (int c = 0; c < NCOL / 16; ++c)
                *(float4*)(drow + c * 4) = *(const float4*)(srw + c * 4);
        }
    }
}

extern "C" void kernel_launch(void* const* d_in, const int* in_sizes, int n_in,
                              void* d_out, int out_size, void* d_ws, size_t ws_size,
                              hipStream_t stream) {
    const float* x     = (const float*)d_in[0];
    const int*   ei    = (const int*)d_in[1];
    const float* ew    = (const float*)d_in[2];
    const int*   et    = (const int*)d_in[3];
    const float* W1    = (const float*)d_in[4];
    const float* root1 = (const float*)d_in[5];
    const float* bias1 = (const float*)d_in[6];
    const float* W2    = (const float*)d_in[7];
    const float* root2 = (const float*)d_in[8];
    const float* bias2 = (const float*)d_in[9];

    const int N = in_sizes[0] / F_DIM;
    const int E = in_sizes[2];
    const int M2 = N * R_NUM;
    const int* srcp = ei;
    const int* dstp = ei + E;

    // ws layout (int units unless noted):
    // mm[16] | invc[N] | deg2[8N] | rp2[8N] | bsum[256] | bmn[512] | bmx[512] |
    // erec[E] | xb[N*128 u16] | hb[N*128 u16] | wt1[9*128*128 u16] |
    // wt2[9*64*128 u16] | y[N*1024 u16]
    int* base = (int*)d_ws;
    float* mm    = (float*)base;
    float* invc  = (float*)(base + 16);
    int*   deg2  = base + 16 + N;
    int*   rp2   = deg2 + M2;
    int*   bsum  = rp2 + M2;
    float* bmn   = (float*)(bsum + 256);
    float* bmx   = bmn + 512;
    unsigned* erec = (unsigned*)(bmx + 512);
    unsigned short* xb  = (unsigned short*)(erec + E);
    unsigned short* hb  = xb + (size_t)N * 128;
    unsigned short* wt1 = hb + (size_t)N * 128;
    unsigned short* wt2 = wt1 + 9 * 128 * 128;
    unsigned short* y   = wt2 + 9 * 64 * 128;   // N * 8 * 128

    const int TB = 256;
    int blocksE = (E + TB - 1) / TB;
    int nb = (M2 + 2047) / 2048;   // 196 <= 256
    long x4 = (long)N * 128 / 4;

    // ---- setup (5 launches; scan3 folded into fill2/gather) ----
    hipMemsetAsync(deg2, 0, (size_t)M2 * sizeof(int), stream);
    setupA<<<512, TB, 0, stream>>>(ew, dstp, et, E, deg2, bmn, bmx,
                                   x, xb, x4, W1, root1, W2, root2, wt1, wt2);
    scan1_kernel<<<nb, TB, 0, stream>>>(deg2, rp2, bsum, invc, M2, N);
    scan2_mm<<<1, TB, 0, stream>>>(bsum, nb, bmn, bmx, mm);
    fill2_kernel<<<blocksE, TB, 0, stream>>>(srcp, dstp, et, ew, mm, invc,
                                             rp2, bsum, erec, E);

    int gatB = (int)(((long)M2 * 16 + TB - 1) / TB);   // 25000
    int gB = (N + 63) / 64;                            // 782

    // ---- layer 1: 128 -> 128, relu, bf16 out ----
    gather_y<<<gatB, TB, 0, stream>>>(rp2, bsum, erec, xb, y, N);
    gemm_y<H_DIM, true, true><<<gB, TB, 0, stream>>>(y, xb, wt1, bias1, hb, nullptr, N);
    // ---- layer 2: 128 -> 64, f32 out ----
    gather_y<<<gatB, TB, 0, stream>>>(rp2, bsum, erec, hb, y, N);
    gemm_y<O_DIM, false, false><<<gB, TB, 0, stream>>>(y, hb, wt2, bias2, nullptr,
                                                       (float*)d_out, N);
}

// Round 13
// 298.210 us; speedup vs baseline: 1.1080x; 1.0841x over previous
//
#include <hip/hip_runtime.h>

// Problem constants: N=50000, E=600000, F=128, H=128, O=64, R=8
#define F_DIM 128
#define H_DIM 128
#define O_DIM 64
#define R_NUM 8

typedef __attribute__((ext_vector_type(8))) short bf16x8;
typedef __attribute__((ext_vector_type(4))) float f32x4;
typedef __attribute__((ext_vector_type(8))) unsigned short u16x8;

union V8 { bf16x8 v; short4 h[2]; };

__device__ __forceinline__ unsigned short f2b(float f) {
    unsigned u = __float_as_uint(f);
    u += 0x7FFFu + ((u >> 16) & 1u);   // RNE
    return (unsigned short)(u >> 16);
}
__device__ __forceinline__ float b2f(unsigned short b) {
    return __uint_as_float(((unsigned)b) << 16);
}

// ---- fused setup A: (dst,rel) degree count + per-block ew min/max ;
//      x -> bf16 ; both weight stacks transpose+convert. Grid MUST be 512. ----
__global__ __launch_bounds__(256) void setupA(
    const float* __restrict__ ew, const int* __restrict__ dst,
    const int* __restrict__ et, int E, int* __restrict__ deg2,
    float* __restrict__ bmn, float* __restrict__ bmx,
    const float* __restrict__ x, unsigned short* __restrict__ xb, long x4,
    const float* __restrict__ W1, const float* __restrict__ root1,
    const float* __restrict__ W2, const float* __restrict__ root2,
    unsigned short* __restrict__ wt1, unsigned short* __restrict__ wt2) {
    __shared__ float smn[256], smx[256];
    const int tid = threadIdx.x;
    const int gstride = gridDim.x * blockDim.x;
    int g0 = blockIdx.x * blockDim.x + tid;

    float mn = 1e30f, mx = -1e30f;
    for (int i = g0; i < E; i += gstride) {
        atomicAdd(&deg2[dst[i] * R_NUM + et[i]], 1);
        float v = ew[i];
        mn = fminf(mn, v);
        mx = fmaxf(mx, v);
    }
    smn[tid] = mn; smx[tid] = mx;
    __syncthreads();
    for (int s = 128; s > 0; s >>= 1) {
        if (tid < s) {
            smn[tid] = fminf(smn[tid], smn[tid + s]);
            smx[tid] = fmaxf(smx[tid], smx[tid + s]);
        }
        __syncthreads();
    }
    if (tid == 0) { bmn[blockIdx.x] = smn[0]; bmx[blockIdx.x] = smx[0]; }

    for (long i = g0; i < x4; i += gstride) {
        float4 v = ((const float4*)x)[i];
        ushort4 o;
        o.x = f2b(v.x); o.y = f2b(v.y); o.z = f2b(v.z); o.w = f2b(v.w);
        ((ushort4*)xb)[i] = o;
    }

    const int n1 = 9 * 128 * 128, n2 = 9 * 64 * 128;
    for (int idx = g0; idx < n1 + n2; idx += gstride) {
        if (idx < n1) {
            int r = idx / (128 * 128), rem = idx % (128 * 128);
            int n = rem / 128, k = rem % 128;
            float v = (r < 8) ? W1[((size_t)r * 128 + k) * 128 + n]
                              : root1[(size_t)k * 128 + n];
            wt1[idx] = f2b(v);
        } else {
            int j = idx - n1;
            int r = j / (64 * 128), rem = j % (64 * 128);
            int n = rem / 128, k = rem % 128;
            float v = (r < 8) ? W2[((size_t)r * 128 + k) * 64 + n]
                              : root2[(size_t)k * 64 + n];
            wt2[j] = f2b(v);
        }
    }
}

// ---- scan1: per-2048-chunk exclusive scan of deg2 + fused invc ----
__global__ void scan1_kernel(const int* __restrict__ deg, int* __restrict__ rp,
                             int* __restrict__ bsum, float* __restrict__ invc,
                             int M, int N) {
    __shared__ int s[256];
    int base = blockIdx.x * 2048;
    int t = threadIdx.x;
    int v[8]; int loc = 0;
#pragma unroll
    for (int i = 0; i < 8; ++i) {
        int idx = base + t * 8 + i;
        v[i] = (idx < M) ? deg[idx] : 0;
        loc += v[i];
    }
    int node = blockIdx.x * 256 + t;
    if (node < N) invc[node] = 1.0f / (float)max(loc, 1);
    s[t] = loc;
    __syncthreads();
    for (int off = 1; off < 256; off <<= 1) {
        int x = (t >= off) ? s[t - off] : 0;
        __syncthreads();
        s[t] += x;
        __syncthreads();
    }
    int run = s[t] - loc;
#pragma unroll
    for (int i = 0; i < 8; ++i) {
        int idx = base + t * 8 + i;
        if (idx < M) rp[idx] = run;
        run += v[i];
    }
    if (t == 255) bsum[blockIdx.x] = s[255];
}

// ---- scan2 + global min/max reduce (single block) ----
// After this, rp2 stays CHUNK-LOCAL; consumers add bsum[i>>11].
__global__ void scan2_mm(int* bsum, int nb, const float* __restrict__ bmn,
                         const float* __restrict__ bmx, float* mm) {
    __shared__ int s[256];
    __shared__ float smn[256], smx[256];
    int t = threadIdx.x;
    int v = (t < nb) ? bsum[t] : 0;
    s[t] = v;
    smn[t] = fminf(bmn[t], bmn[t + 256]);
    smx[t] = fmaxf(bmx[t], bmx[t + 256]);
    __syncthreads();
    for (int off = 1; off < 256; off <<= 1) {
        int x = (t >= off) ? s[t - off] : 0;
        __syncthreads();
        s[t] += x;
        __syncthreads();
    }
    if (t < nb) bsum[t] = s[t] - v;
    for (int r = 128; r > 0; r >>= 1) {
        if (t < r) {
            smn[t] = fminf(smn[t], smn[t + r]);
            smx[t] = fmaxf(smx[t], smx[t + r]);
        }
        __syncthreads();
    }
    if (t == 0) { mm[0] = smn[0]; mm[1] = smx[0]; }
}

// ---- CSR fill: pos = (rp2[i]++ local) + bsum[i>>11] ;
//      erec = bf16(w_norm * invc[dst])<<17 | src   (4B record)
__global__ void fill2_kernel(const int* __restrict__ src, const int* __restrict__ dst,
                             const int* __restrict__ et, const float* __restrict__ ew,
                             const float* __restrict__ mm, const float* __restrict__ invc,
                             int* __restrict__ rp2, const int* __restrict__ bsum,
                             unsigned* __restrict__ erec, int E) {
    int e = blockIdx.x * blockDim.x + threadIdx.x;
    if (e >= E) return;
    int d = dst[e];
    int i = d * R_NUM + et[e];
    int pos = atomicAdd(&rp2[i], 1) + bsum[i >> 11];
    float mn = mm[0], mx = mm[1];
    unsigned wq = f2b((ew[e] - mn) / (mx - mn + 1e-8f) * invc[d]);
    erec[pos] = (wq << 17) | (unsigned)src[e];
}

// ---- gather (layer 1): y[seg] = sum_{e in seg} w_premul * inp[src] ----------
__global__ __launch_bounds__(256) void gather_y(
    const int* __restrict__ rp2, const int* __restrict__ bsum,
    const unsigned* __restrict__ erec,
    const unsigned short* __restrict__ inp,
    unsigned short* __restrict__ y, int N) {
    int gid = blockIdx.x * 256 + threadIdx.x;
    int seg = gid >> 4;
    int n = seg >> 3;
    if (n >= N) return;
    int j = (gid & 15) * 8;
    int beg = (seg == 0) ? 0 : rp2[seg - 1] + bsum[(seg - 1) >> 11];
    int end = rp2[seg] + bsum[seg >> 11];
    float acc[8] = {0.f, 0.f, 0.f, 0.f, 0.f, 0.f, 0.f, 0.f};
    int k = beg;
    for (; k + 2 <= end; k += 2) {
        unsigned r0 = erec[k], r1 = erec[k + 1];
        float w0 = __uint_as_float((r0 >> 1) & 0x7FFF8000u);
        float w1 = __uint_as_float((r1 >> 1) & 0x7FFF8000u);
        u16x8 v0 = *(const u16x8*)(inp + (size_t)(r0 & 0x1FFFFu) * 128 + j);
        u16x8 v1 = *(const u16x8*)(inp + (size_t)(r1 & 0x1FFFFu) * 128 + j);
#pragma unroll
        for (int c = 0; c < 8; ++c) acc[c] += w0 * b2f(v0[c]);
#pragma unroll
        for (int c = 0; c < 8; ++c) acc[c] += w1 * b2f(v1[c]);
    }
    if (k < end) {
        unsigned r0 = erec[k];
        float w0 = __uint_as_float((r0 >> 1) & 0x7FFF8000u);
        u16x8 v0 = *(const u16x8*)(inp + (size_t)(r0 & 0x1FFFFu) * 128 + j);
#pragma unroll
        for (int c = 0; c < 8; ++c) acc[c] += w0 * b2f(v0[c]);
    }
    u16x8 o;
#pragma unroll
    for (int c = 0; c < 8; ++c) o[c] = f2b(acc[c]);
    *(u16x8*)(y + (size_t)seg * 128 + j) = o;
}

// =====================================================================
// gemm_y (R9 known-best, layer 1 only): out = sum_r y[n][r]@Wt[r] +
// inp[n]@Wt[8] + bias. LDS-staged both operands, 2 barriers per r.
// MFMA roles (verified R4-R12): A=Wt frag, B=y frag, D: col=node,
// row=quad*4+i=out-col.
// =====================================================================
template <int NCOL, bool RELU>
__global__ __launch_bounds__(256) void gemm_y(
    const unsigned short* __restrict__ y,
    const unsigned short* __restrict__ inp,
    const unsigned short* __restrict__ Wt,
    const float* __restrict__ bias,
    unsigned short* __restrict__ outb, int N)
{
    constexpr int NT = NCOL / 16;
    __shared__ unsigned short smem[64 * 132 + NCOL * 132];
    unsigned short* ys  = smem;
    unsigned short* wsd = smem + 64 * 132;

    const int tid = threadIdx.x;
    const int w = tid >> 6, lane = tid & 63;
    const int quad = lane >> 4, l15 = lane & 15;
    const int n0 = blockIdx.x * 64;

    f32x4 acc[NT];
#pragma unroll
    for (int nt = 0; nt < NT; ++nt) acc[nt] = (f32x4){0.f, 0.f, 0.f, 0.f};

    for (int r = 0; r < 9; ++r) {
#pragma unroll
        for (int it = 0; it < NCOL / 16; ++it) {
            int u = tid + it * 256;
            int row = u >> 4, seg = u & 15;
            V8 v;
            v.v = *(const bf16x8*)(Wt + ((size_t)r * NCOL + row) * 128 + seg * 8);
            *(short4*)&wsd[row * 132 + seg * 8]     = v.h[0];
            *(short4*)&wsd[row * 132 + seg * 8 + 4] = v.h[1];
        }
#pragma unroll
        for (int it = 0; it < 4; ++it) {
            int u = tid + it * 256;
            int row = u >> 4, seg = u & 15;
            int node = n0 + row;
            if (node >= N) node = N - 1;
            const unsigned short* src = (r < 8)
                ? y + ((size_t)node * R_NUM + r) * 128 + seg * 8
                : inp + (size_t)node * 128 + seg * 8;
            V8 v; v.v = *(const bf16x8*)src;
            *(short4*)&ys[row * 132 + seg * 8]     = v.h[0];
            *(short4*)&ys[row * 132 + seg * 8 + 4] = v.h[1];
        }
        __syncthreads();
        const unsigned short* yrow = ys + (size_t)(w * 16 + l15) * 132 + quad * 8;
#pragma unroll
        for (int k2 = 0; k2 < 4; ++k2) {
            V8 b;
            b.h[0] = *(const short4*)(yrow + k2 * 32);
            b.h[1] = *(const short4*)(yrow + k2 * 32 + 4);
#pragma unroll
            for (int nt = 0; nt < NT; ++nt) {
                const unsigned short* ar = wsd + (size_t)(nt * 16 + l15) * 132
                                           + k2 * 32 + quad * 8;
                V8 av;
                av.h[0] = *(const short4*)ar;
                av.h[1] = *(const short4*)(ar + 4);
                acc[nt] = __builtin_amdgcn_mfma_f32_16x16x32_bf16(av.v, b.v, acc[nt], 0, 0, 0);
            }
        }
        __syncthreads();
    }

    const int gn = tid >> 2, gq = tid & 3;
    const int gnode = n0 + gn;
    unsigned short* stg = smem;   // 64 x 136
#pragma unroll
    for (int nt = 0; nt < NT; ++nt) {
        int c0 = nt * 16 + quad * 4;
        float4 bs = *(const float4*)(bias + c0);
        float v0 = acc[nt][0] + bs.x, v1 = acc[nt][1] + bs.y;
        float v2 = acc[nt][2] + bs.z, v3 = acc[nt][3] + bs.w;
        if (RELU) {
            v0 = fmaxf(v0, 0.f); v1 = fmaxf(v1, 0.f);
            v2 = fmaxf(v2, 0.f); v3 = fmaxf(v3, 0.f);
        }
        short4 o;
        o.x = (short)f2b(v0); o.y = (short)f2b(v1);
        o.z = (short)f2b(v2); o.w = (short)f2b(v3);
        *(short4*)&stg[(w * 16 + l15) * 136 + c0] = o;
    }
    __syncthreads();
    if (gnode < N) {
        const unsigned short* srw = stg + gn * 136 + gq * (NCOL / 4);
        unsigned short* drow = outb + (size_t)gnode * NCOL + gq * (NCOL / 4);
#pragma unroll
        for (int c = 0; c < NCOL / 32; ++c)
            *(bf16x8*)(drow + c * 8) = *(const bf16x8*)(srw + c * 8);
    }
}

// =====================================================================
// gemm_proj2 (layer 2 transform-first): proj2[r][n][c] = h[n] @ W2t[r],
// r=0..8 (r=8 = root). Block = 64 nodes. h staged once; W2t[r] staged
// per r (2 barriers). Per-wave LDS transpose -> fully coalesced 16B
// global stores ([r][n][c] layout: 64 nodes x 128B contiguous per r).
// =====================================================================
__global__ __launch_bounds__(256) void gemm_proj2(
    const unsigned short* __restrict__ h,     // N x 128 bf16
    const unsigned short* __restrict__ Wt,    // 9 x 64 x 128 bf16
    unsigned short* __restrict__ proj2,       // 9 x N x 64 bf16
    int N)
{
    __shared__ unsigned short hs[64 * 132];
    __shared__ unsigned short wsd[64 * 132];
    __shared__ unsigned short ts[64 * 68];    // per-wave private 16x68 regions

    const int tid = threadIdx.x;
    const int w = tid >> 6, lane = tid & 63;
    const int quad = lane >> 4, l15 = lane & 15;
    const int n0 = blockIdx.x * 64;

    // stage h slice once (64 nodes x 128)
#pragma unroll
    for (int it = 0; it < 4; ++it) {
        int u = tid + it * 256;
        int row = u >> 4, seg = u & 15;
        int node = n0 + row;
        if (node >= N) node = N - 1;
        V8 v; v.v = *(const bf16x8*)(h + (size_t)node * 128 + seg * 8);
        *(short4*)&hs[row * 132 + seg * 8]     = v.h[0];
        *(short4*)&hs[row * 132 + seg * 8 + 4] = v.h[1];
    }

    for (int r = 0; r < 9; ++r) {
        // stage W2t[r] (64 rows x 128)
#pragma unroll
        for (int it = 0; it < 4; ++it) {
            int u = tid + it * 256;
            int row = u >> 4, seg = u & 15;
            V8 v;
            v.v = *(const bf16x8*)(Wt + ((size_t)r * 64 + row) * 128 + seg * 8);
            *(short4*)&wsd[row * 132 + seg * 8]     = v.h[0];
            *(short4*)&wsd[row * 132 + seg * 8 + 4] = v.h[1];
        }
        __syncthreads();
        // MFMA: wave w -> nodes w*16..+15, 64 cols (NT=4)
        f32x4 acc[4];
#pragma unroll
        for (int nt = 0; nt < 4; ++nt) acc[nt] = (f32x4){0.f, 0.f, 0.f, 0.f};
        const unsigned short* yrow = hs + (size_t)(w * 16 + l15) * 132 + quad * 8;
#pragma unroll
        for (int k2 = 0; k2 < 4; ++k2) {
            V8 b;
            b.h[0] = *(const short4*)(yrow + k2 * 32);
            b.h[1] = *(const short4*)(yrow + k2 * 32 + 4);
#pragma unroll
            for (int nt = 0; nt < 4; ++nt) {
                const unsigned short* ar = wsd + (size_t)(nt * 16 + l15) * 132
                                           + k2 * 32 + quad * 8;
                V8 av;
                av.h[0] = *(const short4*)ar;
                av.h[1] = *(const short4*)(ar + 4);
                acc[nt] = __builtin_amdgcn_mfma_f32_16x16x32_bf16(av.v, b.v, acc[nt], 0, 0, 0);
            }
        }
        // per-wave transpose through private ts region (no extra barrier)
        unsigned short* tw = ts + w * 16 * 68;
#pragma unroll
        for (int nt = 0; nt < 4; ++nt) {
            int c0 = nt * 16 + quad * 4;
            short4 o;
            o.x = (short)f2b(acc[nt][0]); o.y = (short)f2b(acc[nt][1]);
            o.z = (short)f2b(acc[nt][2]); o.w = (short)f2b(acc[nt][3]);
            *(short4*)&tw[l15 * 68 + c0] = o;
        }
        // readback + coalesced global store: 2 instrs of 16B/lane
#pragma unroll
        for (int jj = 0; jj < 2; ++jj) {
            int rl = (lane >> 3) + 8 * jj;
            int off = (lane & 7) * 8;
            int g = n0 + w * 16 + rl;
            V8 v;
            v.h[0] = *(const short4*)&tw[rl * 68 + off];
            v.h[1] = *(const short4*)&tw[rl * 68 + off + 4];
            if (g < N)
                *(bf16x8*)(proj2 + ((size_t)r * N + g) * 64 + off) = v.v;
        }
        __syncthreads();
    }
}

// =====================================================================
// gather_out2 (layer 2): out[n] = sum_{e in(n)} w_premul * proj2[r][src]
//                                 + proj2[8][n] + bias      (f32 out)
// 8 lanes per node, 8 channels each; r-loop unrolled with per-(n,r)
// segment bounds from chunk-local rp2 + bsum.
// =====================================================================
__global__ __launch_bounds__(256) void gather_out2(
    const int* __restrict__ rp2, const int* __restrict__ bsum,
    const unsigned* __restrict__ erec,
    const unsigned short* __restrict__ proj2,   // 9 x N x 64 bf16
    const float* __restrict__ bias,
    float* __restrict__ out, int N)
{
    int gid = blockIdx.x * 256 + threadIdx.x;
    int n = gid >> 3;
    if (n >= N) return;
    int j = (gid & 7) * 8;

    int base = n * R_NUM;
    int bs_n = bsum[base >> 11];
    int4 ea = *(const int4*)(rp2 + base);
    int4 eb = *(const int4*)(rp2 + base + 4);
    int ends[8] = {ea.x + bs_n, ea.y + bs_n, ea.z + bs_n, ea.w + bs_n,
                   eb.x + bs_n, eb.y + bs_n, eb.z + bs_n, eb.w + bs_n};
    int k = (n == 0) ? 0 : rp2[base - 1] + bsum[(base - 1) >> 11];

    float acc[8] = {0.f, 0.f, 0.f, 0.f, 0.f, 0.f, 0.f, 0.f};
#pragma unroll
    for (int r = 0; r < 8; ++r) {
        int end = ends[r];
        for (; k < end; ++k) {
            unsigned rec = erec[k];
            float wgt = __uint_as_float((rec >> 1) & 0x7FFF8000u);
            u16x8 v = *(const u16x8*)(proj2 + ((size_t)r * N + (rec & 0x1FFFFu)) * 64 + j);
#pragma unroll
            for (int c = 0; c < 8; ++c) acc[c] += wgt * b2f(v[c]);
        }
    }
    // self/root + bias
    u16x8 sv = *(const u16x8*)(proj2 + ((size_t)8 * N + n) * 64 + j);
    float4 b0 = *(const float4*)(bias + j);
    float4 b1 = *(const float4*)(bias + j + 4);
    float* o = out + (size_t)n * 64 + j;
    o[0] = acc[0] + b2f(sv[0]) + b0.x;
    o[1] = acc[1] + b2f(sv[1]) + b0.y;
    o[2] = acc[2] + b2f(sv[2]) + b0.z;
    o[3] = acc[3] + b2f(sv[3]) + b0.w;
    o[4] = acc[4] + b2f(sv[4]) + b1.x;
    o[5] = acc[5] + b2f(sv[5]) + b1.y;
    o[6] = acc[6] + b2f(sv[6]) + b1.z;
    o[7] = acc[7] + b2f(sv[7]) + b1.w;
}

extern "C" void kernel_launch(void* const* d_in, const int* in_sizes, int n_in,
                              void* d_out, int out_size, void* d_ws, size_t ws_size,
                              hipStream_t stream) {
    const float* x     = (const float*)d_in[0];
    const int*   ei    = (const int*)d_in[1];
    const float* ew    = (const float*)d_in[2];
    const int*   et    = (const int*)d_in[3];
    const float* W1    = (const float*)d_in[4];
    const float* root1 = (const float*)d_in[5];
    const float* bias1 = (const float*)d_in[6];
    const float* W2    = (const float*)d_in[7];
    const float* root2 = (const float*)d_in[8];
    const float* bias2 = (const float*)d_in[9];

    const int N = in_sizes[0] / F_DIM;
    const int E = in_sizes[2];
    const int M2 = N * R_NUM;
    const int* srcp = ei;
    const int* dstp = ei + E;

    // ws layout (int units unless noted):
    // mm[16] | invc[N] | deg2[8N] | rp2[8N] | bsum[256] | bmn[512] | bmx[512] |
    // erec[E] | xb[N*128 u16] | hb[N*128 u16] | wt1[9*128*128 u16] |
    // wt2[9*64*128 u16] | y[N*1024 u16] (proj2 aliases y: 9*N*64 u16)
    int* base = (int*)d_ws;
    float* mm    = (float*)base;
    float* invc  = (float*)(base + 16);
    int*   deg2  = base + 16 + N;
    int*   rp2   = deg2 + M2;
    int*   bsum  = rp2 + M2;
    float* bmn   = (float*)(bsum + 256);
    float* bmx   = bmn + 512;
    unsigned* erec = (unsigned*)(bmx + 512);
    unsigned short* xb  = (unsigned short*)(erec + E);
    unsigned short* hb  = xb + (size_t)N * 128;
    unsigned short* wt1 = hb + (size_t)N * 128;
    unsigned short* wt2 = wt1 + 9 * 128 * 128;
    unsigned short* y   = wt2 + 9 * 64 * 128;   // N * 8 * 128
    unsigned short* proj2 = y;                  // 9 * N * 64 (aliases y)

    const int TB = 256;
    int blocksE = (E + TB - 1) / TB;
    int nb = (M2 + 2047) / 2048;   // 196 <= 256
    long x4 = (long)N * 128 / 4;

    // ---- setup ----
    hipMemsetAsync(deg2, 0, (size_t)M2 * sizeof(int), stream);
    setupA<<<512, TB, 0, stream>>>(ew, dstp, et, E, deg2, bmn, bmx,
                                   x, xb, x4, W1, root1, W2, root2, wt1, wt2);
    scan1_kernel<<<nb, TB, 0, stream>>>(deg2, rp2, bsum, invc, M2, N);
    scan2_mm<<<1, TB, 0, stream>>>(bsum, nb, bmn, bmx, mm);
    fill2_kernel<<<blocksE, TB, 0, stream>>>(srcp, dstp, et, ew, mm, invc,
                                             rp2, bsum, erec, E);

    int gatB = (int)(((long)M2 * 16 + TB - 1) / TB);   // 25000
    int gB = (N + 63) / 64;                            // 782

    // ---- layer 1 (aggregate-first): gather y ; gemm -> hb (bf16, relu) ----
    gather_y<<<gatB, TB, 0, stream>>>(rp2, bsum, erec, xb, y, N);
    gemm_y<H_DIM, true><<<gB, TB, 0, stream>>>(y, xb, wt1, bias1, hb, N);

    // ---- layer 2 (transform-first): proj2 = h@W2[r] ; gather -> out ----
    gemm_proj2<<<gB, TB, 0, stream>>>(hb, wt2, proj2, N);
    int g2B = (int)(((long)N * 8 + TB - 1) / TB);      // 1563
    gather_out2<<<g2B, TB, 0, stream>>>(rp2, bsum, erec, proj2, bias2,
                                        (float*)d_out, N);
}